// Round 2
// baseline (1330.347 us; speedup 1.0000x reference)
//
#include <hip/hip_runtime.h>
#include <hip/hip_bf16.h>

typedef unsigned int uint;

#define T_STEPS 32

// ---- workspace dword offsets ----
#define OFF_CTX    0          // 4096*64 floats
#define OFF_WIH2   262144     // 6144  (half2-packed wih^T  [4][384][4])
#define OFF_WHH2   268288     // 24576 (half2-packed whh^T  [16][384][4])
#define OFF_PROJT  292864     // 8192  (proj_w^T fp32 [128][64])
#define OFF_DW0P   301056     // 6144  (drift_w0^T f16 [12][128][4], k pad 89->96)
#define OFF_DW1P   307200     // 8192
#define OFF_DW2P   315392     // 8192
#define OFF_GW0P   323584     // 6144
#define OFF_GW1P   329728     // 8192  -> total 337920 dwords = 1.29 MB

typedef _Float16 h2v __attribute__((ext_vector_type(2)));

__device__ inline uint pack2f(float a, float b) {
  _Float16 ha = (_Float16)a, hb = (_Float16)b;
  unsigned short ua, ub;
  __builtin_memcpy(&ua, &ha, 2);
  __builtin_memcpy(&ub, &hb, 2);
  return (uint)ua | ((uint)ub << 16);
}

__device__ inline float dot2(uint w, uint a, float acc) {
#if __has_builtin(__builtin_amdgcn_fdot2)
  union U { uint u; h2v h; };
  U uw, ua; uw.u = w; ua.u = a;
  return __builtin_amdgcn_fdot2(uw.h, ua.h, acc, false);
#else
  union U { uint u; _Float16 h[2]; };
  U uw, ua; uw.u = w; ua.u = a;
  return acc + (float)uw.h[0] * (float)ua.h[0] + (float)uw.h[1] * (float)ua.h[1];
#endif
}

#define DOT4(accv, wv, xv)                                             \
  accv = dot2((wv).x, (xv).x, accv); accv = dot2((wv).y, (xv).y, accv);\
  accv = dot2((wv).z, (xv).z, accv); accv = dot2((wv).w, (xv).w, accv);

__device__ inline float sigm(float x) { return 1.f / (1.f + __expf(-x)); }
__device__ inline float tanh_f(float x) {
  float ax = fabsf(x);
  float e = __expf(2.f * ax);
  float t = 1.f - 2.f / (e + 1.f);
  return copysignf(t, x);
}
__device__ inline float silu_f(float x) { return x / (1.f + __expf(-x)); }

// ======================= weight pre-pack =======================
__global__ __launch_bounds__(256) void prep_kernel(
    const float* __restrict__ wih, const float* __restrict__ whh,
    const float* __restrict__ pw,
    const float* __restrict__ dw0, const float* __restrict__ dw1,
    const float* __restrict__ dw2, const float* __restrict__ gw0,
    const float* __restrict__ gw1, float* __restrict__ ws) {
  int id = blockIdx.x * 256 + threadIdx.x;
  uint* wsu = (uint*)ws;
  if (id < 6144) {                       // wih^T packed: [k4<4][u<384][i<4]
    int k4 = id / 1536, rem = id % 1536, u = rem >> 2, i = rem & 3;
    int k0 = k4 * 8 + i * 2;
    float a = (k0     < 25) ? wih[u * 25 + k0]     : 0.f;
    float b = (k0 + 1 < 25) ? wih[u * 25 + k0 + 1] : 0.f;
    wsu[OFF_WIH2 + id] = pack2f(a, b);
  } else if (id < 30720) {               // whh^T packed: [k4<16][u<384][i<4]
    int t = id - 6144;
    int k4 = t / 1536, rem = t % 1536, u = rem >> 2, i = rem & 3;
    int k0 = k4 * 8 + i * 2;
    wsu[OFF_WHH2 + t] = pack2f(whh[u * 128 + k0], whh[u * 128 + k0 + 1]);
  } else if (id < 38912) {               // proj^T fp32 [k<128][o<64]
    int t = id - 30720;
    int k = t >> 6, o = t & 63;
    ws[OFF_PROJT + t] = pw[o * 128 + k];
  } else if (id < 45056) {               // drift_w0^T [k4<12][j<128][i<4], k<89
    int t = id - 38912;
    int k4 = t / 512, rem = t % 512, j = rem >> 2, i = rem & 3;
    int k0 = k4 * 8 + i * 2;
    float a = (k0     < 89) ? dw0[j * 89 + k0]     : 0.f;
    float b = (k0 + 1 < 89) ? dw0[j * 89 + k0 + 1] : 0.f;
    wsu[OFF_DW0P + t] = pack2f(a, b);
  } else if (id < 53248) {               // drift_w1^T [k4<16][j<128][i<4]
    int t = id - 45056;
    int k4 = t / 512, rem = t % 512, j = rem >> 2, i = rem & 3;
    int k0 = k4 * 8 + i * 2;
    wsu[OFF_DW1P + t] = pack2f(dw1[j * 128 + k0], dw1[j * 128 + k0 + 1]);
  } else if (id < 61440) {               // drift_w2^T
    int t = id - 53248;
    int k4 = t / 512, rem = t % 512, j = rem >> 2, i = rem & 3;
    int k0 = k4 * 8 + i * 2;
    wsu[OFF_DW2P + t] = pack2f(dw2[j * 128 + k0], dw2[j * 128 + k0 + 1]);
  } else if (id < 67584) {               // diff_w0^T (k<89)
    int t = id - 61440;
    int k4 = t / 512, rem = t % 512, j = rem >> 2, i = rem & 3;
    int k0 = k4 * 8 + i * 2;
    float a = (k0     < 89) ? gw0[j * 89 + k0]     : 0.f;
    float b = (k0 + 1 < 89) ? gw0[j * 89 + k0 + 1] : 0.f;
    wsu[OFF_GW0P + t] = pack2f(a, b);
  } else if (id < 75776) {               // diff_w1^T
    int t = id - 67584;
    int k4 = t / 512, rem = t % 512, j = rem >> 2, i = rem & 3;
    int k0 = k4 * 8 + i * 2;
    wsu[OFF_GW1P + t] = pack2f(gw1[j * 128 + k0], gw1[j * 128 + k0 + 1]);
  }
}

// ======================= GRU encoder =======================
// grid 256 blocks x 512 threads; block owns 16 batch rows.
// thread: j2 = tid&63 -> hidden units {j2, j2+64}; q = tid>>6 -> rows {2q, 2q+1}
__global__ __launch_bounds__(512) void gru_kernel(
    const float* __restrict__ ctp, const uint* __restrict__ wsu,
    const float* __restrict__ gbias, const float* __restrict__ gbn,
    const float* __restrict__ projb, float* __restrict__ ws) {
  __shared__ __align__(16) uint x2[T_STEPS * 16 * 16];  // [t][r][k2] half2, 32 KB
  __shared__ __align__(16) uint h2[16 * 64];            // [r][k2] half2 of h
  const int tid = threadIdx.x;
  const int rb = blockIdx.x * 16;

  // stage symmetrized features for all 32 timesteps
  for (int idx = tid; idx < T_STEPS * 16 * 16; idx += 512) {
    int k2 = idx & 15, r = (idx >> 4) & 15, t = idx >> 8;
    const float* base = ctp + ((rb + r) * T_STEPS + t) * 25;
    int k0 = k2 * 2;
    float v0 = 0.f, v1 = 0.f;
    if (k0 < 25)     { int i5 = k0 / 5,      j5 = k0 % 5;      v0 = 0.5f * (base[i5*5+j5] + base[j5*5+i5]); }
    if (k0 + 1 < 25) { int i5 = (k0+1) / 5,  j5 = (k0+1) % 5;  v1 = 0.5f * (base[i5*5+j5] + base[j5*5+i5]); }
    x2[idx] = pack2f(v0, v1);
  }

  const int j2 = tid & 63;
  const int q  = tid >> 6;
  const uint* wih2 = wsu + OFF_WIH2;
  const uint* whh2 = wsu + OFF_WHH2;
  float br[2], bz[2], bg[2], bn[2];
#pragma unroll
  for (int m = 0; m < 2; m++) {
    int u = j2 + 64 * m;
    br[m] = gbias[u]; bz[m] = gbias[128 + u]; bg[m] = gbias[256 + u]; bn[m] = gbn[u];
  }
  float hp[2][2] = {{0.f, 0.f}, {0.f, 0.f}};  // [unit m][row s]
  __syncthreads();

  for (int t = 0; t < T_STEPS; t++) {
    float ar[2][2], az[2][2], ai[2][2], ah[2][2];
#pragma unroll
    for (int m = 0; m < 2; m++)
#pragma unroll
      for (int s = 0; s < 2; s++) { ar[m][s] = br[m]; az[m][s] = bz[m]; ai[m][s] = bg[m]; ah[m][s] = 0.f; }

    const uint* xr0 = &x2[(t * 16 + 2 * q) * 16];
    const uint* xr1 = xr0 + 16;
#pragma unroll
    for (int k4 = 0; k4 < 4; k4++) {
      uint4 xa = *(const uint4*)(xr0 + k4 * 4);
      uint4 xb = *(const uint4*)(xr1 + k4 * 4);
#pragma unroll
      for (int m = 0; m < 2; m++) {
        int u = j2 + 64 * m;
        uint4 wr = *(const uint4*)(wih2 + (k4 * 384 + u) * 4);
        uint4 wz = *(const uint4*)(wih2 + (k4 * 384 + 128 + u) * 4);
        uint4 wg = *(const uint4*)(wih2 + (k4 * 384 + 256 + u) * 4);
        DOT4(ar[m][0], wr, xa); DOT4(ar[m][1], wr, xb);
        DOT4(az[m][0], wz, xa); DOT4(az[m][1], wz, xb);
        DOT4(ai[m][0], wg, xa); DOT4(ai[m][1], wg, xb);
      }
    }
    if (t > 0) {
      const uint* hr0 = &h2[(2 * q) * 64];
      const uint* hr1 = hr0 + 64;
#pragma unroll 4
      for (int k4 = 0; k4 < 16; k4++) {
        uint4 xa = *(const uint4*)(hr0 + k4 * 4);
        uint4 xb = *(const uint4*)(hr1 + k4 * 4);
#pragma unroll
        for (int m = 0; m < 2; m++) {
          int u = j2 + 64 * m;
          uint4 wr = *(const uint4*)(whh2 + (k4 * 384 + u) * 4);
          uint4 wz = *(const uint4*)(whh2 + (k4 * 384 + 128 + u) * 4);
          uint4 wg = *(const uint4*)(whh2 + (k4 * 384 + 256 + u) * 4);
          DOT4(ar[m][0], wr, xa); DOT4(ar[m][1], wr, xb);
          DOT4(az[m][0], wz, xa); DOT4(az[m][1], wz, xb);
          DOT4(ah[m][0], wg, xa); DOT4(ah[m][1], wg, xb);
        }
      }
    }
    __syncthreads();  // all reads of h2 complete
    _Float16* hh = (_Float16*)h2;
#pragma unroll
    for (int m = 0; m < 2; m++)
#pragma unroll
      for (int s = 0; s < 2; s++) {
        float r = sigm(ar[m][s]);
        float z = sigm(az[m][s]);
        float g = tanh_f(ai[m][s] + r * (ah[m][s] + bn[m]));
        float hn = (1.f - z) * g + z * hp[m][s];
        hp[m][s] = hn;
        hh[(2 * q + s) * 128 + j2 + 64 * m] = (_Float16)hn;
      }
    __syncthreads();  // h2 visible for next step
  }

  // ctx = hT @ proj_w^T + proj_b
  const float* pT = ws + OFF_PROJT;
  const _Float16* hh = (const _Float16*)h2;
  int o = tid & 63;
#pragma unroll
  for (int s = 0; s < 2; s++) {
    int r = 2 * q + s;
    float acc = projb[o];
    for (int k = 0; k < 128; k++)
      acc = fmaf(pT[k * 64 + o], (float)hh[r * 128 + k], acc);
    ws[OFF_CTX + (rb + r) * 64 + o] = acc;
  }
}

// ======================= SDE kernel =======================
__device__ inline void mlp_layer(const uint* __restrict__ pw, const uint* pact,
                                 int astride, int kq, const float* __restrict__ pb,
                                 _Float16* pout, int em, int jq) {
  float acc[4];
#pragma unroll
  for (int m = 0; m < 4; m++) acc[m] = pb[jq + 32 * m];
  const uint* arow = pact + em * astride;
  for (int k4 = 0; k4 < kq; k4++) {
    uint4 a = *(const uint4*)(arow + k4 * 4);
#pragma unroll
    for (int m = 0; m < 4; m++) {
      uint4 w = *(const uint4*)(pw + (k4 * 128 + jq + 32 * m) * 4);
      DOT4(acc[m], w, a);
    }
  }
#pragma unroll
  for (int m = 0; m < 4; m++) pout[em * 128 + jq + 32 * m] = (_Float16)silu_f(acc[m]);
}

__device__ inline float mm5(float A, float Bv, int i, int j) {
  float c = 0.f;
#pragma unroll
  for (int k = 0; k < 5; k++)
    c = fmaf(__shfl(A, i * 5 + k, 32), __shfl(Bv, k * 5 + j, 32), c);
  return c;
}

// grid 256 x 512; block owns 16 batch elements.
__global__ __launch_bounds__(512) void sde_kernel(
    const float* __restrict__ ctp, const float* __restrict__ dWp,
    const float* __restrict__ ws, const uint* __restrict__ wsu,
    const float* __restrict__ db0, const float* __restrict__ db1,
    const float* __restrict__ db2, const float* __restrict__ w3,
    const float* __restrict__ b3, const float* __restrict__ gb0,
    const float* __restrict__ gb1, const float* __restrict__ gw2,
    const float* __restrict__ gb2, float* __restrict__ outp) {
  __shared__ __align__(16) uint inp2[16 * 48];   // [e][96 halves]: sigma|ctx|pad
  __shared__ __align__(16) uint acta[16 * 64];
  __shared__ __align__(16) uint actb[16 * 64];
  __shared__ float sig_s[16 * 28];               // fp32 sigma (25 used, pad 28)
  __shared__ float coeff_s[16 * 16];
  const int tid = threadIdx.x;
  const int eb = blockIdx.x * 16;
  _Float16* inph = (_Float16*)inp2;

  for (int idx = tid; idx < 16 * 64; idx += 512) {
    int e = idx >> 6, c = idx & 63;
    inph[e * 96 + 25 + c] = (_Float16)ws[OFF_CTX + (eb + e) * 64 + c];
  }
  for (int idx = tid; idx < 400; idx += 512) {
    int e = idx / 25, k = idx % 25;
    int i5 = k / 5, j5 = k % 5;
    const float* base = ctp + ((eb + e) * T_STEPS + 31) * 25;
    float v = 0.5f * (base[i5 * 5 + j5] + base[j5 * 5 + i5]);
    sig_s[e * 28 + k] = v;
    inph[e * 96 + k] = (_Float16)v;
  }
  for (int idx = tid; idx < 16 * 7; idx += 512) {
    int e = idx / 7, p = idx % 7;
    inph[e * 96 + 89 + p] = (_Float16)0.f;
  }
  const int em = tid >> 5;     // element 0..15
  const int jq = tid & 31;     // -> units jq + {0,32,64,96}
  __syncthreads();

  for (int s = 0; s < 5; s++) {
    mlp_layer(wsu + OFF_DW0P, inp2, 48, 12, db0, (_Float16*)acta, em, jq);
    __syncthreads();
    mlp_layer(wsu + OFF_DW1P, acta, 64, 16, db1, (_Float16*)actb, em, jq);
    __syncthreads();
    mlp_layer(wsu + OFF_DW2P, actb, 64, 16, db2, (_Float16*)acta, em, jq);
    __syncthreads();
    if (tid < 240) {  // drift out: coeff = DT * (w3 @ h + b3)
      int e = tid / 15, o = tid % 15;
      const _Float16* hh = (const _Float16*)acta;
      float acc = b3[o];
      for (int k = 0; k < 128; k++) acc = fmaf(w3[o * 128 + k], (float)hh[e * 128 + k], acc);
      coeff_s[e * 16 + o] = 0.2f * acc;
    }
    __syncthreads();
    mlp_layer(wsu + OFF_GW0P, inp2, 48, 12, gb0, (_Float16*)actb, em, jq);
    __syncthreads();
    mlp_layer(wsu + OFF_GW1P, actb, 64, 16, gb1, (_Float16*)acta, em, jq);
    __syncthreads();
    if (tid < 240) {  // diffusion out: coeff += softplus(gw2 @ g + gb2) * dW
      int e = tid / 15, o = tid % 15;
      const _Float16* hh = (const _Float16*)acta;
      float acc = gb2[o];
      for (int k = 0; k < 128; k++) acc = fmaf(gw2[o * 128 + k], (float)hh[e * 128 + k], acc);
      float sp = (acc > 20.f) ? acc : __logf(1.f + __expf(acc));
      coeff_s[e * 16 + o] += sp * dWp[((eb + e) * 5 + s) * 15 + o];
    }
    __syncthreads();

    // ---- geometry: 32-lane group per element, lane holds matrix elem (i,j) ----
    {
      int e = em;
      int lane = tid & 31;
      int li = (lane < 25) ? lane : 0;
      int ii = li / 5, jj = li % 5;
      float del = (ii == jj) ? 1.f : 0.f;
      float S = sig_s[e * 28 + li];
      float tr = 0.f;
#pragma unroll
      for (int d = 0; d < 5; d++) tr += __shfl(S, d * 6, 32);
      // Newton-Schulz coupled sqrt of A = S/tr (eigs in (0,1])
      float Y = S * (1.f / tr);
      float Z = del;
      for (int it = 0; it < 15; it++) {
        float P  = mm5(Z, Y, ii, jj);
        float Tm = 1.5f * del - 0.5f * P;
        float Yn = mm5(Y, Tm, ii, jj);
        float Zn = mm5(Tm, Z, ii, jj);
        Y = Yn; Z = Zn;
      }
      float L = Y * sqrtf(tr);
      // tangent matrix a from coeff in orthonormal SPD basis
      float av;
      if (ii == jj) av = coeff_s[e * 16 + ii];
      else {
        int p = ii < jj ? ii : jj, qq = ii < jj ? jj : ii;
        av = coeff_s[e * 16 + 5 + (p * (9 - p)) / 2 + (qq - p - 1)] * 0.70710678f;
      }
      // expm(a): Horner Taylor-12
      float M = del;
#pragma unroll
      for (int n = 12; n >= 1; n--) {
        float P = mm5(av, M, ii, jj);
        M = del + P * (1.f / (float)n);
      }
      float P2 = mm5(L, M, ii, jj);
      float S2 = mm5(P2, L, ii, jj);
      S2 = 0.5f * (S2 + __shfl(S2, jj * 5 + ii, 32));
      if (lane < 25) {
        sig_s[e * 28 + li] = S2;
        inph[e * 96 + li] = (_Float16)S2;
      }
    }
    __syncthreads();
  }

  for (int idx = tid; idx < 400; idx += 512) {
    int e = idx / 25, k = idx % 25;
    outp[(eb + e) * 25 + k] = sig_s[e * 28 + k];
  }
}

extern "C" void kernel_launch(void* const* d_in, const int* in_sizes, int n_in,
                              void* d_out, int out_size, void* d_ws, size_t ws_size,
                              hipStream_t stream) {
  const float* ctp = (const float*)d_in[0];
  const float* dWp = (const float*)d_in[1];
  const float* wih = (const float*)d_in[2];
  const float* whh = (const float*)d_in[3];
  const float* gb  = (const float*)d_in[4];
  const float* gbn = (const float*)d_in[5];
  const float* pw  = (const float*)d_in[6];
  const float* pb  = (const float*)d_in[7];
  const float* dw0 = (const float*)d_in[8];
  const float* db0 = (const float*)d_in[9];
  const float* dw1 = (const float*)d_in[10];
  const float* db1 = (const float*)d_in[11];
  const float* dw2 = (const float*)d_in[12];
  const float* db2 = (const float*)d_in[13];
  const float* dw3 = (const float*)d_in[14];
  const float* db3 = (const float*)d_in[15];
  const float* gw0 = (const float*)d_in[16];
  const float* gb0 = (const float*)d_in[17];
  const float* gw1 = (const float*)d_in[18];
  const float* gb1 = (const float*)d_in[19];
  const float* gw2 = (const float*)d_in[20];
  const float* gb2 = (const float*)d_in[21];
  float* ws = (float*)d_ws;
  uint* wsu = (uint*)d_ws;

  hipLaunchKernelGGL(prep_kernel, dim3(296), dim3(256), 0, stream,
                     wih, whh, pw, dw0, dw1, dw2, gw0, gw1, ws);
  hipLaunchKernelGGL(gru_kernel, dim3(256), dim3(512), 0, stream,
                     ctp, wsu, gb, gbn, pb, ws);
  hipLaunchKernelGGL(sde_kernel, dim3(256), dim3(512), 0, stream,
                     ctp, dWp, ws, wsu, db0, db1, db2, dw3, db3,
                     gb0, gb1, gw2, gb2, (float*)d_out);
}

// Round 3
// 300.081 us; speedup vs baseline: 4.4333x; 4.4333x over previous
//
#include <hip/hip_runtime.h>
#include <hip/hip_bf16.h>

typedef unsigned int uint;

#define T_STEPS 32

// ---- workspace dword offsets ----
#define OFF_CTX    0          // 4096*64 floats
#define OFF_WB     262144     // 30720 uints: GRU B-frag packed weights (f16)
#define OFF_PROJT  292864     // 8192  (proj_w^T fp32 [128][64])
#define OFF_DW0P   301056     // 6144  (drift_w0^T f16 [12][128][4], k pad 89->96)
#define OFF_DW1P   307200     // 8192
#define OFF_DW2P   315392     // 8192
#define OFF_GW0P   323584     // 6144
#define OFF_GW1P   329728     // 8192
#define OFF_W3P    337920     // 960   (drift_w3 f16 [15][64 uints])
#define OFF_GW2P   338880     // 960   (diff_w2  f16 [15][64 uints])
// total 339840 dwords = 1.30 MB

typedef _Float16 h2v  __attribute__((ext_vector_type(2)));
typedef _Float16 half8 __attribute__((ext_vector_type(8)));
typedef float    f32x4 __attribute__((ext_vector_type(4)));

__device__ inline uint pack2f(float a, float b) {
  _Float16 ha = (_Float16)a, hb = (_Float16)b;
  unsigned short ua, ub;
  __builtin_memcpy(&ua, &ha, 2);
  __builtin_memcpy(&ub, &hb, 2);
  return (uint)ua | ((uint)ub << 16);
}

__device__ inline float dot2(uint w, uint a, float acc) {
#if __has_builtin(__builtin_amdgcn_fdot2)
  union U { uint u; h2v h; };
  U uw, ua; uw.u = w; ua.u = a;
  return __builtin_amdgcn_fdot2(uw.h, ua.h, acc, false);
#else
  union U { uint u; _Float16 h[2]; };
  U uw, ua; uw.u = w; ua.u = a;
  return acc + (float)uw.h[0] * (float)ua.h[0] + (float)uw.h[1] * (float)ua.h[1];
#endif
}

#define DOT4(accv, wv, xv)                                             \
  accv = dot2((wv).x, (xv).x, accv); accv = dot2((wv).y, (xv).y, accv);\
  accv = dot2((wv).z, (xv).z, accv); accv = dot2((wv).w, (xv).w, accv);

__device__ inline float sigm(float x) { return 1.f / (1.f + __expf(-x)); }
__device__ inline float tanh_f(float x) {
  float ax = fabsf(x);
  float e = __expf(2.f * ax);
  float t = 1.f - 2.f / (e + 1.f);
  return copysignf(t, x);
}
__device__ inline float silu_f(float x) { return x / (1.f + __expf(-x)); }

__device__ inline void unpack4(uint2 v, float* o) {
  union { uint u; _Float16 h[2]; } a, b; a.u = v.x; b.u = v.y;
  o[0] = (float)a.h[0]; o[1] = (float)a.h[1];
  o[2] = (float)b.h[0]; o[3] = (float)b.h[1];
}

// ======================= weight pre-pack =======================
__global__ __launch_bounds__(256) void prep_kernel(
    const float* __restrict__ wih, const float* __restrict__ whh,
    const float* __restrict__ pw,
    const float* __restrict__ dw0, const float* __restrict__ dw1,
    const float* __restrict__ dw2, const float* __restrict__ gw0,
    const float* __restrict__ gw1, const float* __restrict__ dw3,
    const float* __restrict__ gw2, float* __restrict__ ws) {
  int id = blockIdx.x * 256 + threadIdx.x;
  uint* wsu = (uint*)ws;
  if (id < 30720) {
    // GRU B-fragments: idx = (((w*3+nt)*5+kt)*64 + lane)*4 + i
    int i = id & 3, l = (id >> 2) & 63, t3 = id >> 8;
    int kt = t3 % 5, ntw = t3 / 5;             // ntw = w*3+nt in [0,24)
    int u = (ntw / 3) * 48 + (ntw % 3) * 16 + (l & 15);
    int k = kt * 32 + ((l >> 4) << 3) + i * 2;
    float a, b;
    if (kt == 0) {
      a = (k     < 25) ? wih[u * 25 + k]     : 0.f;
      b = (k + 1 < 25) ? wih[u * 25 + k + 1] : 0.f;
    } else {
      a = whh[u * 128 + (k - 32)];
      b = whh[u * 128 + (k - 31)];
    }
    wsu[OFF_WB + id] = pack2f(a, b);
  } else if (id < 38912) {               // proj^T fp32 [k<128][o<64]
    int t = id - 30720;
    int k = t >> 6, o = t & 63;
    ws[OFF_PROJT + t] = pw[o * 128 + k];
  } else if (id < 45056) {               // drift_w0^T [k4<12][j<128][i<4], k<89
    int t = id - 38912;
    int k4 = t / 512, rem = t % 512, j = rem >> 2, i = rem & 3;
    int k0 = k4 * 8 + i * 2;
    float a = (k0     < 89) ? dw0[j * 89 + k0]     : 0.f;
    float b = (k0 + 1 < 89) ? dw0[j * 89 + k0 + 1] : 0.f;
    wsu[OFF_DW0P + t] = pack2f(a, b);
  } else if (id < 53248) {               // drift_w1^T [k4<16][j<128][i<4]
    int t = id - 45056;
    int k4 = t / 512, rem = t % 512, j = rem >> 2, i = rem & 3;
    int k0 = k4 * 8 + i * 2;
    wsu[OFF_DW1P + t] = pack2f(dw1[j * 128 + k0], dw1[j * 128 + k0 + 1]);
  } else if (id < 61440) {               // drift_w2^T
    int t = id - 53248;
    int k4 = t / 512, rem = t % 512, j = rem >> 2, i = rem & 3;
    int k0 = k4 * 8 + i * 2;
    wsu[OFF_DW2P + t] = pack2f(dw2[j * 128 + k0], dw2[j * 128 + k0 + 1]);
  } else if (id < 67584) {               // diff_w0^T (k<89)
    int t = id - 61440;
    int k4 = t / 512, rem = t % 512, j = rem >> 2, i = rem & 3;
    int k0 = k4 * 8 + i * 2;
    float a = (k0     < 89) ? gw0[j * 89 + k0]     : 0.f;
    float b = (k0 + 1 < 89) ? gw0[j * 89 + k0 + 1] : 0.f;
    wsu[OFF_GW0P + t] = pack2f(a, b);
  } else if (id < 75776) {               // diff_w1^T
    int t = id - 67584;
    int k4 = t / 512, rem = t % 512, j = rem >> 2, i = rem & 3;
    int k0 = k4 * 8 + i * 2;
    wsu[OFF_GW1P + t] = pack2f(gw1[j * 128 + k0], gw1[j * 128 + k0 + 1]);
  } else if (id < 76736) {               // drift_w3 f16 [o][k2]
    int t = id - 75776;
    int o = t >> 6, k2 = t & 63;
    wsu[OFF_W3P + t] = pack2f(dw3[o * 128 + 2 * k2], dw3[o * 128 + 2 * k2 + 1]);
  } else if (id < 77696) {               // diff_w2 f16 [o][k2]
    int t = id - 76736;
    int o = t >> 6, k2 = t & 63;
    wsu[OFF_GW2P + t] = pack2f(gw2[o * 128 + 2 * k2], gw2[o * 128 + 2 * k2 + 1]);
  }
}

// ======================= GRU encoder (MFMA) =======================
// grid 256 x 512; block owns 16 batch rows (M=16). 8 waves x 48 units (N),
// K = 160 (x pad 25->32 | h 128). B-frags resident in VGPRs across all t.
__global__ __launch_bounds__(512) void gru_kernel(
    const float* __restrict__ ctp, const uint* __restrict__ wsu,
    const float* __restrict__ gbias, const float* __restrict__ gbn,
    const float* __restrict__ projb, float* __restrict__ ws) {
  __shared__ __align__(16) _Float16 x2[T_STEPS * 4 * 16 * 8];  // [t][q][m][j] 32KB
  __shared__ __align__(16) _Float16 hf[4 * 4 * 16 * 8];        // [kt][q][m][j] 4KB
  __shared__ __align__(16) _Float16 gbuf[512 * 20];            // [u'][m pad20] 20.5KB
  const int tid = threadIdx.x;
  const int rb = blockIdx.x * 16;
  uint* x2u = (uint*)x2;

  // stage symmetrized features in A-frag layout
  for (int idx = tid; idx < T_STEPS * 16 * 16; idx += 512) {
    int k2 = idx & 15, r = (idx >> 4) & 15, t = idx >> 8;
    const float* base = ctp + ((rb + r) * T_STEPS + t) * 25;
    int k0 = 2 * k2;
    float v0 = 0.f, v1 = 0.f;
    if (k0 < 25)     { int i5 = k0 / 5,     j5 = k0 % 5;     v0 = 0.5f * (base[i5*5+j5] + base[j5*5+i5]); }
    if (k0 + 1 < 25) { int i5 = (k0+1) / 5, j5 = (k0+1) % 5; v1 = 0.5f * (base[i5*5+j5] + base[j5*5+i5]); }
    int q = k2 >> 2, jh = k2 & 3;
    x2u[((t * 4 + q) * 16 + r) * 4 + jh] = pack2f(v0, v1);
  }
  // zero h fragments
  uint* hfu = (uint*)hf;
  for (int idx = tid; idx < 1024; idx += 512) hfu[idx] = 0u;

  // B-fragment preload (registers, resident across t-loop)
  const int w = tid >> 6, l = tid & 63;
  const int lm = l & 15, lq = l >> 4;
  union FB { uint4 u; half8 h; };
  FB Bf[3][5];
  const uint4* wb = (const uint4*)(wsu + OFF_WB);
#pragma unroll
  for (int nt = 0; nt < 3; nt++)
#pragma unroll
    for (int kt = 0; kt < 5; kt++)
      Bf[nt][kt].u = wb[((w * 3 + nt) * 5 + kt) * 64 + l];

  // gate-phase constants
  const int hu = tid & 127, mg = tid >> 7;
  const int kt4 = hu >> 5, q2 = (hu >> 3) & 3, jj = hu & 7;
  const float br = gbias[hu], bz = gbias[128 + hu], bg = gbias[256 + hu], bn = gbn[hu];
  float hprev[4] = {0.f, 0.f, 0.f, 0.f};
  __syncthreads();

  for (int t = 0; t < T_STEPS; t++) {
    // A fragments
    half8 ax = *(const half8*)(x2 + ((t * 4 + lq) * 16 + lm) * 8);
    half8 ah[4];
#pragma unroll
    for (int kk = 0; kk < 4; kk++)
      ah[kk] = *(const half8*)(hf + ((kk * 4 + lq) * 16 + lm) * 8);

#pragma unroll
    for (int nt = 0; nt < 3; nt++) {
      f32x4 cz = {0.f, 0.f, 0.f, 0.f};
      f32x4 cx = __builtin_amdgcn_mfma_f32_16x16x32_f16(ax, Bf[nt][0].h, cz, 0, 0, 0);
      f32x4 ch = {0.f, 0.f, 0.f, 0.f};
#pragma unroll
      for (int kk = 0; kk < 4; kk++)
        ch = __builtin_amdgcn_mfma_f32_16x16x32_f16(ah[kk], Bf[nt][1 + kk].h, ch, 0, 0, 0);
      int ubase = w * 48 + nt * 16;       // wave-uniform tile base
      int u = ubase + lm;
      if (ubase < 256) {                  // r or z: sum x+h parts
        uint2 pk;
        pk.x = pack2f(cx[0] + ch[0], cx[1] + ch[1]);
        pk.y = pack2f(cx[2] + ch[2], cx[3] + ch[3]);
        *(uint2*)&gbuf[u * 20 + lq * 4] = pk;
      } else {                            // g: keep ig (row u) and hg (row u+128)
        uint2 pa, pb2;
        pa.x  = pack2f(cx[0], cx[1]); pa.y  = pack2f(cx[2], cx[3]);
        pb2.x = pack2f(ch[0], ch[1]); pb2.y = pack2f(ch[2], ch[3]);
        *(uint2*)&gbuf[u * 20 + lq * 4] = pa;
        *(uint2*)&gbuf[(u + 128) * 20 + lq * 4] = pb2;
      }
    }
    __syncthreads();

    // gate nonlinearity: thread owns (hu, rows mg*4..mg*4+3)
    float rp[4], zp[4], ip[4], hp4[4];
    unpack4(*(const uint2*)&gbuf[hu * 20 + mg * 4], rp);
    unpack4(*(const uint2*)&gbuf[(128 + hu) * 20 + mg * 4], zp);
    unpack4(*(const uint2*)&gbuf[(256 + hu) * 20 + mg * 4], ip);
    unpack4(*(const uint2*)&gbuf[(384 + hu) * 20 + mg * 4], hp4);
#pragma unroll
    for (int s = 0; s < 4; s++) {
      float r = sigm(rp[s] + br);
      float z = sigm(zp[s] + bz);
      float g = tanh_f(ip[s] + bg + r * (hp4[s] + bn));
      float hn = (1.f - z) * g + z * hprev[s];
      hprev[s] = hn;
      hf[((kt4 * 4 + q2) * 16 + (mg * 4 + s)) * 8 + jj] = (_Float16)hn;
    }
    __syncthreads();
  }

  // ctx = hT @ proj_w^T + proj_b  (scalar, reads hf)
  const float* pT = ws + OFF_PROJT;
  const int o = tid & 63, rq = tid >> 6;
#pragma unroll
  for (int s = 0; s < 2; s++) {
    int r = 2 * rq + s;
    float acc = projb[o];
    for (int k = 0; k < 128; k++) {
      int a = k >> 5, b = (k >> 3) & 3, c = k & 7;
      acc = fmaf(pT[k * 64 + o], (float)hf[((a * 4 + b) * 16 + r) * 8 + c], acc);
    }
    ws[OFF_CTX + (rb + r) * 64 + o] = acc;
  }
}

// ======================= SDE kernel =======================
__device__ inline void mlp_layer(const uint* __restrict__ pw, const uint* pact,
                                 int astride, int kq, const float* __restrict__ pb,
                                 _Float16* pout, int em, int jq) {
  float acc[4];
#pragma unroll
  for (int m = 0; m < 4; m++) acc[m] = pb[jq + 32 * m];
  const uint* arow = pact + em * astride;
  for (int k4 = 0; k4 < kq; k4++) {
    uint4 a = *(const uint4*)(arow + k4 * 4);
#pragma unroll
    for (int m = 0; m < 4; m++) {
      uint4 w = *(const uint4*)(pw + (k4 * 128 + jq + 32 * m) * 4);
      DOT4(acc[m], w, a);
    }
  }
#pragma unroll
  for (int m = 0; m < 4; m++) pout[em * 128 + jq + 32 * m] = (_Float16)silu_f(acc[m]);
}

__device__ inline float mm5(float A, float Bv, int i, int j) {
  float c = 0.f;
#pragma unroll
  for (int k = 0; k < 5; k++)
    c = fmaf(__shfl(A, i * 5 + k, 32), __shfl(Bv, k * 5 + j, 32), c);
  return c;
}

__device__ inline void stageW(uint* dst, const uint* __restrict__ src, int n4, int tid) {
  const uint4* s = (const uint4*)src;
  uint4* d = (uint4*)dst;
  for (int i = tid; i < n4; i += 512) d[i] = s[i];
}

// grid 256 x 512; block owns 16 batch elements. Weights staged to LDS per layer.
__global__ __launch_bounds__(512) void sde_kernel(
    const float* __restrict__ ctp, const float* __restrict__ dWp,
    const float* __restrict__ ws, const uint* __restrict__ wsu,
    const float* __restrict__ db0, const float* __restrict__ db1,
    const float* __restrict__ db2, const float* __restrict__ b3,
    const float* __restrict__ gb0, const float* __restrict__ gb1,
    const float* __restrict__ gb2, float* __restrict__ outp) {
  __shared__ __align__(16) uint wbuf[8192];      // 32KB layer weights
  __shared__ __align__(16) uint inp2[16 * 48];   // [e][96 halves]
  __shared__ __align__(16) uint acta[16 * 64];
  __shared__ __align__(16) uint actb[16 * 64];
  __shared__ __align__(16) uint w3s[960];
  __shared__ __align__(16) uint gw2s[960];
  __shared__ float sig_s[16 * 28];
  __shared__ float coeff_s[16 * 16];
  const int tid = threadIdx.x;
  const int eb = blockIdx.x * 16;
  _Float16* inph = (_Float16*)inp2;

  for (int i = tid; i < 960; i += 512) {
    w3s[i]  = wsu[OFF_W3P + i];
    gw2s[i] = wsu[OFF_GW2P + i];
  }
  for (int idx = tid; idx < 16 * 64; idx += 512) {
    int e = idx >> 6, c = idx & 63;
    inph[e * 96 + 25 + c] = (_Float16)ws[OFF_CTX + (eb + e) * 64 + c];
  }
  for (int idx = tid; idx < 400; idx += 512) {
    int e = idx / 25, k = idx % 25;
    int i5 = k / 5, j5 = k % 5;
    const float* base = ctp + ((eb + e) * T_STEPS + 31) * 25;
    float v = 0.5f * (base[i5 * 5 + j5] + base[j5 * 5 + i5]);
    sig_s[e * 28 + k] = v;
    inph[e * 96 + k] = (_Float16)v;
  }
  for (int idx = tid; idx < 16 * 7; idx += 512) {
    int e = idx / 7, p = idx % 7;
    inph[e * 96 + 89 + p] = (_Float16)0.f;
  }
  const int em = tid >> 5;
  const int jq = tid & 31;
  __syncthreads();

  for (int s = 0; s < 5; s++) {
    stageW(wbuf, wsu + OFF_DW0P, 1536, tid);
    __syncthreads();
    mlp_layer(wbuf, inp2, 48, 12, db0, (_Float16*)acta, em, jq);
    __syncthreads();
    stageW(wbuf, wsu + OFF_DW1P, 2048, tid);
    __syncthreads();
    mlp_layer(wbuf, acta, 64, 16, db1, (_Float16*)actb, em, jq);
    __syncthreads();
    stageW(wbuf, wsu + OFF_DW2P, 2048, tid);
    __syncthreads();
    mlp_layer(wbuf, actb, 64, 16, db2, (_Float16*)acta, em, jq);
    __syncthreads();
    // drift head (LDS w3s) + stage diffusion layer 0 concurrently
    stageW(wbuf, wsu + OFF_GW0P, 1536, tid);
    if (tid < 240) {
      int e = tid / 15, o = tid % 15;
      float acc = b3[o];
      const uint* au = acta + e * 64;
      const uint4* wrow = (const uint4*)(w3s + o * 64);
#pragma unroll
      for (int k4 = 0; k4 < 16; k4++) {
        uint4 wv = wrow[k4];
        uint4 av = *(const uint4*)(au + k4 * 4);
        DOT4(acc, wv, av);
      }
      coeff_s[e * 16 + o] = 0.2f * acc;
    }
    __syncthreads();
    mlp_layer(wbuf, inp2, 48, 12, gb0, (_Float16*)actb, em, jq);
    __syncthreads();
    stageW(wbuf, wsu + OFF_GW1P, 2048, tid);
    __syncthreads();
    mlp_layer(wbuf, actb, 64, 16, gb1, (_Float16*)acta, em, jq);
    __syncthreads();
    if (tid < 240) {  // diffusion head: coeff += softplus(gw2 @ g + gb2) * dW
      int e = tid / 15, o = tid % 15;
      float acc = gb2[o];
      const uint* au = acta + e * 64;
      const uint4* wrow = (const uint4*)(gw2s + o * 64);
#pragma unroll
      for (int k4 = 0; k4 < 16; k4++) {
        uint4 wv = wrow[k4];
        uint4 av = *(const uint4*)(au + k4 * 4);
        DOT4(acc, wv, av);
      }
      float sp = (acc > 20.f) ? acc : __logf(1.f + __expf(acc));
      coeff_s[e * 16 + o] += sp * dWp[((eb + e) * 5 + s) * 15 + o];
    }
    __syncthreads();

    // ---- geometry: 32-lane group per element ----
    {
      int e = em;
      int lane = tid & 31;
      int li = (lane < 25) ? lane : 0;
      int ii = li / 5, jj2 = li % 5;
      float del = (ii == jj2) ? 1.f : 0.f;
      float S = sig_s[e * 28 + li];
      float tr = 0.f;
#pragma unroll
      for (int d = 0; d < 5; d++) tr += __shfl(S, d * 6, 32);
      float Y = S * (1.f / tr);
      float Z = del;
      for (int it = 0; it < 15; it++) {
        float P  = mm5(Z, Y, ii, jj2);
        float Tm = 1.5f * del - 0.5f * P;
        float Yn = mm5(Y, Tm, ii, jj2);
        float Zn = mm5(Tm, Z, ii, jj2);
        Y = Yn; Z = Zn;
      }
      float L = Y * sqrtf(tr);
      float av;
      if (ii == jj2) av = coeff_s[e * 16 + ii];
      else {
        int p = ii < jj2 ? ii : jj2, qq = ii < jj2 ? jj2 : ii;
        av = coeff_s[e * 16 + 5 + (p * (9 - p)) / 2 + (qq - p - 1)] * 0.70710678f;
      }
      float M = del;
#pragma unroll
      for (int n = 12; n >= 1; n--) {
        float P = mm5(av, M, ii, jj2);
        M = del + P * (1.f / (float)n);
      }
      float P2 = mm5(L, M, ii, jj2);
      float S2 = mm5(P2, L, ii, jj2);
      S2 = 0.5f * (S2 + __shfl(S2, jj2 * 5 + ii, 32));
      if (lane < 25) {
        sig_s[e * 28 + li] = S2;
        inph[e * 96 + li] = (_Float16)S2;
      }
    }
    __syncthreads();
  }

  for (int idx = tid; idx < 400; idx += 512) {
    int e = idx / 25, k = idx % 25;
    outp[(eb + e) * 25 + k] = sig_s[e * 28 + k];
  }
}

extern "C" void kernel_launch(void* const* d_in, const int* in_sizes, int n_in,
                              void* d_out, int out_size, void* d_ws, size_t ws_size,
                              hipStream_t stream) {
  const float* ctp = (const float*)d_in[0];
  const float* dWp = (const float*)d_in[1];
  const float* wih = (const float*)d_in[2];
  const float* whh = (const float*)d_in[3];
  const float* gb  = (const float*)d_in[4];
  const float* gbn = (const float*)d_in[5];
  const float* pw  = (const float*)d_in[6];
  const float* pb  = (const float*)d_in[7];
  const float* dw0 = (const float*)d_in[8];
  const float* db0 = (const float*)d_in[9];
  const float* dw1 = (const float*)d_in[10];
  const float* db1 = (const float*)d_in[11];
  const float* dw2 = (const float*)d_in[12];
  const float* db2 = (const float*)d_in[13];
  const float* dw3 = (const float*)d_in[14];
  const float* db3 = (const float*)d_in[15];
  const float* gw0 = (const float*)d_in[16];
  const float* gb0 = (const float*)d_in[17];
  const float* gw1 = (const float*)d_in[18];
  const float* gb1 = (const float*)d_in[19];
  const float* gw2 = (const float*)d_in[20];
  const float* gb2 = (const float*)d_in[21];
  float* ws = (float*)d_ws;
  uint* wsu = (uint*)d_ws;

  hipLaunchKernelGGL(prep_kernel, dim3(304), dim3(256), 0, stream,
                     wih, whh, pw, dw0, dw1, dw2, gw0, gw1, dw3, gw2, ws);
  hipLaunchKernelGGL(gru_kernel, dim3(256), dim3(512), 0, stream,
                     ctp, wsu, gb, gbn, pb, ws);
  hipLaunchKernelGGL(sde_kernel, dim3(256), dim3(512), 0, stream,
                     ctp, dWp, ws, wsu, db0, db1, db2, db3,
                     gb0, gb1, gb2, (float*)d_out);
}

// Round 4
// 280.069 us; speedup vs baseline: 4.7501x; 1.0715x over previous
//
#include <hip/hip_runtime.h>
#include <hip/hip_bf16.h>

typedef unsigned int uint;

#define T_STEPS 32

// ---- workspace dword offsets ----
#define OFF_CTX    0          // 4096*64 floats
#define OFF_WB     262144     // 30720 uints: GRU B-frag packed weights (f16)
#define OFF_PROJT  292864     // 8192  (proj_w^T fp32 [128][64])
#define OFF_DW0P   301056     // 6144  (drift_w0^T f16 [12][128][4], k pad 89->96)
#define OFF_DW1P   307200     // 8192
#define OFF_DW2P   315392     // 8192
#define OFF_GW0P   323584     // 6144
#define OFF_GW1P   329728     // 8192
#define OFF_W3P    337920     // 960   (drift_w3 f16 [15][64 uints])
#define OFF_GW2P   338880     // 960   (diff_w2  f16 [15][64 uints])

typedef _Float16 h2v  __attribute__((ext_vector_type(2)));
typedef _Float16 half8 __attribute__((ext_vector_type(8)));
typedef float    f32x4 __attribute__((ext_vector_type(4)));

__device__ inline uint pack2f(float a, float b) {
  _Float16 ha = (_Float16)a, hb = (_Float16)b;
  unsigned short ua, ub;
  __builtin_memcpy(&ua, &ha, 2);
  __builtin_memcpy(&ub, &hb, 2);
  return (uint)ua | ((uint)ub << 16);
}

__device__ inline float dot2(uint w, uint a, float acc) {
#if __has_builtin(__builtin_amdgcn_fdot2)
  union U { uint u; h2v h; };
  U uw, ua; uw.u = w; ua.u = a;
  return __builtin_amdgcn_fdot2(uw.h, ua.h, acc, false);
#else
  union U { uint u; _Float16 h[2]; };
  U uw, ua; uw.u = w; ua.u = a;
  return acc + (float)uw.h[0] * (float)ua.h[0] + (float)uw.h[1] * (float)ua.h[1];
#endif
}

#define DOT4(accv, wv, xv)                                             \
  accv = dot2((wv).x, (xv).x, accv); accv = dot2((wv).y, (xv).y, accv);\
  accv = dot2((wv).z, (xv).z, accv); accv = dot2((wv).w, (xv).w, accv);

__device__ inline float sigm(float x) { return 1.f / (1.f + __expf(-x)); }
__device__ inline float tanh_f(float x) {
  float ax = fabsf(x);
  float e = __expf(2.f * ax);
  float t = 1.f - 2.f / (e + 1.f);
  return copysignf(t, x);
}
__device__ inline float silu_f(float x) { return x / (1.f + __expf(-x)); }

// ======================= weight pre-pack =======================
__global__ __launch_bounds__(256) void prep_kernel(
    const float* __restrict__ wih, const float* __restrict__ whh,
    const float* __restrict__ pw,
    const float* __restrict__ dw0, const float* __restrict__ dw1,
    const float* __restrict__ dw2, const float* __restrict__ gw0,
    const float* __restrict__ gw1, const float* __restrict__ dw3,
    const float* __restrict__ gw2, float* __restrict__ ws) {
  int id = blockIdx.x * 256 + threadIdx.x;
  uint* wsu = (uint*)ws;
  if (id < 30720) {
    // GRU B-frags, unit-major: idx = (((w*3+gi)*5+kt)*64 + l)*4 + i
    // wave w owns hidden units w*16+(l&15); gi in {r,z,g}
    int i = id & 3, l = (id >> 2) & 63, t3 = id >> 8;
    int kt = t3 % 5, wg = t3 / 5;
    int w = wg / 3, gi = wg % 3;
    int row = gi * 128 + w * 16 + (l & 15);
    int k = ((l >> 4) << 3) + i * 2;         // quad*8 + 2i in [0,32)
    float a, b;
    if (kt == 0) {
      a = (k     < 25) ? wih[row * 25 + k]     : 0.f;
      b = (k + 1 < 25) ? wih[row * 25 + k + 1] : 0.f;
    } else {
      int kh = (kt - 1) * 32 + k;
      a = whh[row * 128 + kh];
      b = whh[row * 128 + kh + 1];
    }
    wsu[OFF_WB + id] = pack2f(a, b);
  } else if (id < 38912) {               // proj^T fp32 [k<128][o<64]
    int t = id - 30720;
    int k = t >> 6, o = t & 63;
    ws[OFF_PROJT + t] = pw[o * 128 + k];
  } else if (id < 45056) {               // drift_w0^T [k4<12][j<128][i<4], k<89
    int t = id - 38912;
    int k4 = t / 512, rem = t % 512, j = rem >> 2, i = rem & 3;
    int k0 = k4 * 8 + i * 2;
    float a = (k0     < 89) ? dw0[j * 89 + k0]     : 0.f;
    float b = (k0 + 1 < 89) ? dw0[j * 89 + k0 + 1] : 0.f;
    wsu[OFF_DW0P + t] = pack2f(a, b);
  } else if (id < 53248) {               // drift_w1^T [k4<16][j<128][i<4]
    int t = id - 45056;
    int k4 = t / 512, rem = t % 512, j = rem >> 2, i = rem & 3;
    int k0 = k4 * 8 + i * 2;
    wsu[OFF_DW1P + t] = pack2f(dw1[j * 128 + k0], dw1[j * 128 + k0 + 1]);
  } else if (id < 61440) {               // drift_w2^T
    int t = id - 53248;
    int k4 = t / 512, rem = t % 512, j = rem >> 2, i = rem & 3;
    int k0 = k4 * 8 + i * 2;
    wsu[OFF_DW2P + t] = pack2f(dw2[j * 128 + k0], dw2[j * 128 + k0 + 1]);
  } else if (id < 67584) {               // diff_w0^T (k<89)
    int t = id - 61440;
    int k4 = t / 512, rem = t % 512, j = rem >> 2, i = rem & 3;
    int k0 = k4 * 8 + i * 2;
    float a = (k0     < 89) ? gw0[j * 89 + k0]     : 0.f;
    float b = (k0 + 1 < 89) ? gw0[j * 89 + k0 + 1] : 0.f;
    wsu[OFF_GW0P + t] = pack2f(a, b);
  } else if (id < 75776) {               // diff_w1^T
    int t = id - 67584;
    int k4 = t / 512, rem = t % 512, j = rem >> 2, i = rem & 3;
    int k0 = k4 * 8 + i * 2;
    wsu[OFF_GW1P + t] = pack2f(gw1[j * 128 + k0], gw1[j * 128 + k0 + 1]);
  } else if (id < 76736) {               // drift_w3 f16 [o][k2]
    int t = id - 75776;
    int o = t >> 6, k2 = t & 63;
    wsu[OFF_W3P + t] = pack2f(dw3[o * 128 + 2 * k2], dw3[o * 128 + 2 * k2 + 1]);
  } else if (id < 77696) {               // diff_w2 f16 [o][k2]
    int t = id - 76736;
    int o = t >> 6, k2 = t & 63;
    wsu[OFF_GW2P + t] = pack2f(gw2[o * 128 + 2 * k2], gw2[o * 128 + 2 * k2 + 1]);
  }
}

// ======================= GRU encoder (MFMA, unit-major) =======================
// grid 256 x 512; block owns 16 batch rows. Wave w owns hidden units
// w*16..w*16+15 and computes r,z,ig,hg for them; gates fp32 in-register.
// One barrier per timestep; hf double-buffered.
__global__ __launch_bounds__(512) void gru_kernel(
    const float* __restrict__ ctp, const uint* __restrict__ wsu,
    const float* __restrict__ gbias, const float* __restrict__ gbn,
    const float* __restrict__ projb, float* __restrict__ ws) {
  __shared__ __align__(16) _Float16 x2[T_STEPS][4][16][8];  // A-frags of x, 32KB
  __shared__ __align__(16) _Float16 hf[2][4][4][16][8];     // dbuf A-frags of h, 8KB
  const int tid = threadIdx.x;
  const int rb = blockIdx.x * 16;
  uint* x2u = (uint*)x2;

  // stage symmetrized features in A-frag layout
  for (int idx = tid; idx < T_STEPS * 16 * 16; idx += 512) {
    int k2 = idx & 15, r = (idx >> 4) & 15, t = idx >> 8;
    const float* base = ctp + ((rb + r) * T_STEPS + t) * 25;
    int k0 = 2 * k2;
    float v0 = 0.f, v1 = 0.f;
    if (k0 < 25)     { int i5 = k0 / 5,     j5 = k0 % 5;     v0 = 0.5f * (base[i5*5+j5] + base[j5*5+i5]); }
    if (k0 + 1 < 25) { int i5 = (k0+1) / 5, j5 = (k0+1) % 5; v1 = 0.5f * (base[i5*5+j5] + base[j5*5+i5]); }
    int q = k2 >> 2, jh = k2 & 3;
    x2u[((t * 4 + q) * 16 + r) * 4 + jh] = pack2f(v0, v1);
  }

  const int w = tid >> 6, l = tid & 63;
  const int lm = l & 15, lq = l >> 4;
  const int u = w * 16 + lm;                 // hidden unit this lane owns
  const int ku = u >> 5, qu = (u >> 3) & 3, ju = u & 7;  // h A-frag coords
  union FB { uint4 u4; half8 h; };
  FB Bf[3][5];
  const uint4* wb = (const uint4*)(wsu + OFF_WB);
#pragma unroll
  for (int gi = 0; gi < 3; gi++)
#pragma unroll
    for (int kt = 0; kt < 5; kt++)
      Bf[gi][kt].u4 = wb[((w * 3 + gi) * 5 + kt) * 64 + l];

  const float br = gbias[u], bz = gbias[128 + u], bg = gbias[256 + u], bn = gbn[u];
  float hprev[4] = {0.f, 0.f, 0.f, 0.f};     // rows lq*4+{0..3}, unit u
  __syncthreads();

  for (int t = 0; t < T_STEPS; t++) {
    half8 ax = *(const half8*)(&x2[t][lq][lm][0]);
    f32x4 z4 = {0.f, 0.f, 0.f, 0.f};
    f32x4 cr = __builtin_amdgcn_mfma_f32_16x16x32_f16(ax, Bf[0][0].h, z4, 0, 0, 0);
    f32x4 cz = __builtin_amdgcn_mfma_f32_16x16x32_f16(ax, Bf[1][0].h, z4, 0, 0, 0);
    f32x4 cg = __builtin_amdgcn_mfma_f32_16x16x32_f16(ax, Bf[2][0].h, z4, 0, 0, 0);
    f32x4 ch = {0.f, 0.f, 0.f, 0.f};
    if (t > 0) {
      const int p = t & 1;                   // read parity
#pragma unroll
      for (int kk = 0; kk < 4; kk++) {
        half8 ah = *(const half8*)(&hf[p][kk][lq][lm][0]);
        cr = __builtin_amdgcn_mfma_f32_16x16x32_f16(ah, Bf[0][1 + kk].h, cr, 0, 0, 0);
        cz = __builtin_amdgcn_mfma_f32_16x16x32_f16(ah, Bf[1][1 + kk].h, cz, 0, 0, 0);
        ch = __builtin_amdgcn_mfma_f32_16x16x32_f16(ah, Bf[2][1 + kk].h, ch, 0, 0, 0);
      }
    }
    const int wp = (t + 1) & 1;              // write parity
#pragma unroll
    for (int s = 0; s < 4; s++) {
      float r = sigm(cr[s] + br);
      float z = sigm(cz[s] + bz);
      float g = tanh_f(cg[s] + bg + r * (ch[s] + bn));
      float hn = (1.f - z) * g + z * hprev[s];
      hprev[s] = hn;
      hf[wp][ku][qu][lq * 4 + s][ju] = (_Float16)hn;
    }
    __syncthreads();
  }

  // ctx = hT @ proj_w^T + proj_b   (hT in hf[0])
  const float* pT = ws + OFF_PROJT;
  const int o = tid & 63, rq = tid >> 6;
#pragma unroll
  for (int s = 0; s < 2; s++) {
    int r = 2 * rq + s;
    float acc = projb[o];
    for (int k = 0; k < 128; k++) {
      int a = k >> 5, b = (k >> 3) & 3, c = k & 7;
      acc = fmaf(pT[k * 64 + o], (float)hf[0][a][b][r][c], acc);
    }
    ws[OFF_CTX + (rb + r) * 64 + o] = acc;
  }
}

// ======================= SDE kernel =======================
__device__ inline void mlp_layer(const uint* __restrict__ pw, const uint* pact,
                                 int astride, int kq, const float* __restrict__ pb,
                                 _Float16* pout, int em, int jq) {
  float acc[4];
#pragma unroll
  for (int m = 0; m < 4; m++) acc[m] = pb[jq + 32 * m];
  const uint* arow = pact + em * astride;
  for (int k4 = 0; k4 < kq; k4++) {
    uint4 a = *(const uint4*)(arow + k4 * 4);
#pragma unroll
    for (int m = 0; m < 4; m++) {
      uint4 w = *(const uint4*)(pw + (k4 * 128 + jq + 32 * m) * 4);
      DOT4(acc[m], w, a);
    }
  }
#pragma unroll
  for (int m = 0; m < 4; m++) pout[em * 128 + jq + 32 * m] = (_Float16)silu_f(acc[m]);
}

__device__ inline float mm5(float A, float Bv, int i, int j) {
  float c = 0.f;
#pragma unroll
  for (int k = 0; k < 5; k++)
    c = fmaf(__shfl(A, i * 5 + k, 32), __shfl(Bv, k * 5 + j, 32), c);
  return c;
}

__device__ inline void stageW(uint* dst, const uint* __restrict__ src, int n4, int tid) {
  const uint4* s = (const uint4*)src;
  uint4* d = (uint4*)dst;
  for (int i = tid; i < n4; i += 256) d[i] = s[i];
}

// grid 512 x 256; block owns 8 batch elements -> 2 blocks/CU.
__global__ __launch_bounds__(256) void sde_kernel(
    const float* __restrict__ ctp, const float* __restrict__ dWp,
    const float* __restrict__ ws, const uint* __restrict__ wsu,
    const float* __restrict__ db0, const float* __restrict__ db1,
    const float* __restrict__ db2, const float* __restrict__ b3,
    const float* __restrict__ gb0, const float* __restrict__ gb1,
    const float* __restrict__ gb2, float* __restrict__ outp) {
  __shared__ __align__(16) uint wbuf[8192];      // 32KB layer weights
  __shared__ __align__(16) uint inp2[8 * 48];    // [e][96 halves]
  __shared__ __align__(16) uint acta[8 * 64];
  __shared__ __align__(16) uint actb[8 * 64];
  __shared__ __align__(16) uint w3s[15 * 68];    // rows padded 64->68: bank spread
  __shared__ __align__(16) uint gw2s[15 * 68];
  __shared__ float sig_s[8 * 28];
  __shared__ float coeff_s[8 * 16];
  const int tid = threadIdx.x;
  const int eb = blockIdx.x * 8;
  _Float16* inph = (_Float16*)inp2;

  for (int i = tid; i < 960; i += 256) {
    int o = i >> 6, k2 = i & 63;
    w3s[o * 68 + k2]  = wsu[OFF_W3P + i];
    gw2s[o * 68 + k2] = wsu[OFF_GW2P + i];
  }
  for (int idx = tid; idx < 8 * 64; idx += 256) {
    int e = idx >> 6, c = idx & 63;
    inph[e * 96 + 25 + c] = (_Float16)ws[OFF_CTX + (eb + e) * 64 + c];
  }
  for (int idx = tid; idx < 200; idx += 256) {
    int e = idx / 25, k = idx % 25;
    int i5 = k / 5, j5 = k % 5;
    const float* base = ctp + ((eb + e) * T_STEPS + 31) * 25;
    float v = 0.5f * (base[i5 * 5 + j5] + base[j5 * 5 + i5]);
    sig_s[e * 28 + k] = v;
    inph[e * 96 + k] = (_Float16)v;
  }
  if (tid < 56) {
    int e = tid / 7, p = tid % 7;
    inph[e * 96 + 89 + p] = (_Float16)0.f;
  }
  const int em = tid >> 5;
  const int jq = tid & 31;
  __syncthreads();

  for (int s = 0; s < 5; s++) {
    stageW(wbuf, wsu + OFF_DW0P, 1536, tid);
    __syncthreads();
    mlp_layer(wbuf, inp2, 48, 12, db0, (_Float16*)acta, em, jq);
    __syncthreads();
    stageW(wbuf, wsu + OFF_DW1P, 2048, tid);
    __syncthreads();
    mlp_layer(wbuf, acta, 64, 16, db1, (_Float16*)actb, em, jq);
    __syncthreads();
    stageW(wbuf, wsu + OFF_DW2P, 2048, tid);
    __syncthreads();
    mlp_layer(wbuf, actb, 64, 16, db2, (_Float16*)acta, em, jq);
    __syncthreads();
    // drift head (LDS w3s) + stage diffusion layer 0 concurrently
    stageW(wbuf, wsu + OFF_GW0P, 1536, tid);
    if (tid < 120) {
      int e = tid / 15, o = tid % 15;
      float acc = b3[o];
      const uint* au = acta + e * 64;
      const uint4* wrow = (const uint4*)(w3s + o * 68);
#pragma unroll
      for (int k4 = 0; k4 < 16; k4++) {
        uint4 wv = wrow[k4];
        uint4 av = *(const uint4*)(au + k4 * 4);
        DOT4(acc, wv, av);
      }
      coeff_s[e * 16 + o] = 0.2f * acc;
    }
    __syncthreads();
    mlp_layer(wbuf, inp2, 48, 12, gb0, (_Float16*)actb, em, jq);
    __syncthreads();
    stageW(wbuf, wsu + OFF_GW1P, 2048, tid);
    __syncthreads();
    mlp_layer(wbuf, actb, 64, 16, gb1, (_Float16*)acta, em, jq);
    __syncthreads();
    if (tid < 120) {  // diffusion head: coeff += softplus(gw2 @ g + gb2) * dW
      int e = tid / 15, o = tid % 15;
      float acc = gb2[o];
      const uint* au = acta + e * 64;
      const uint4* wrow = (const uint4*)(gw2s + o * 68);
#pragma unroll
      for (int k4 = 0; k4 < 16; k4++) {
        uint4 wv = wrow[k4];
        uint4 av = *(const uint4*)(au + k4 * 4);
        DOT4(acc, wv, av);
      }
      float sp = (acc > 20.f) ? acc : __logf(1.f + __expf(acc));
      coeff_s[e * 16 + o] += sp * dWp[((eb + e) * 5 + s) * 15 + o];
    }
    __syncthreads();

    // ---- geometry: 32-lane group per element ----
    {
      int e = em;
      int lane = tid & 31;
      int li = (lane < 25) ? lane : 0;
      int ii = li / 5, jj2 = li % 5;
      float del = (ii == jj2) ? 1.f : 0.f;
      float S = sig_s[e * 28 + li];
      float tr = 0.f;
#pragma unroll
      for (int d = 0; d < 5; d++) tr += __shfl(S, d * 6, 32);
      float Y = S * (1.f / tr);
      float Z = del;
      for (int it = 0; it < 15; it++) {
        float P  = mm5(Z, Y, ii, jj2);
        float Tm = 1.5f * del - 0.5f * P;
        float Yn = mm5(Y, Tm, ii, jj2);
        float Zn = mm5(Tm, Z, ii, jj2);
        Y = Yn; Z = Zn;
      }
      float L = Y * sqrtf(tr);
      float av;
      if (ii == jj2) av = coeff_s[e * 16 + ii];
      else {
        int p = ii < jj2 ? ii : jj2, qq = ii < jj2 ? jj2 : ii;
        av = coeff_s[e * 16 + 5 + (p * (9 - p)) / 2 + (qq - p - 1)] * 0.70710678f;
      }
      float M = del;
#pragma unroll
      for (int n = 12; n >= 1; n--) {
        float P = mm5(av, M, ii, jj2);
        M = del + P * (1.f / (float)n);
      }
      float P2 = mm5(L, M, ii, jj2);
      float S2 = mm5(P2, L, ii, jj2);
      S2 = 0.5f * (S2 + __shfl(S2, jj2 * 5 + ii, 32));
      if (lane < 25) {
        sig_s[e * 28 + li] = S2;
        inph[e * 96 + li] = (_Float16)S2;
      }
    }
    __syncthreads();
  }

  for (int idx = tid; idx < 200; idx += 256) {
    int e = idx / 25, k = idx % 25;
    outp[(eb + e) * 25 + k] = sig_s[e * 28 + k];
  }
}

extern "C" void kernel_launch(void* const* d_in, const int* in_sizes, int n_in,
                              void* d_out, int out_size, void* d_ws, size_t ws_size,
                              hipStream_t stream) {
  const float* ctp = (const float*)d_in[0];
  const float* dWp = (const float*)d_in[1];
  const float* wih = (const float*)d_in[2];
  const float* whh = (const float*)d_in[3];
  const float* gb  = (const float*)d_in[4];
  const float* gbn = (const float*)d_in[5];
  const float* pw  = (const float*)d_in[6];
  const float* pb  = (const float*)d_in[7];
  const float* dw0 = (const float*)d_in[8];
  const float* db0 = (const float*)d_in[9];
  const float* dw1 = (const float*)d_in[10];
  const float* db1 = (const float*)d_in[11];
  const float* dw2 = (const float*)d_in[12];
  const float* db2 = (const float*)d_in[13];
  const float* dw3 = (const float*)d_in[14];
  const float* db3 = (const float*)d_in[15];
  const float* gw0 = (const float*)d_in[16];
  const float* gb0 = (const float*)d_in[17];
  const float* gw1 = (const float*)d_in[18];
  const float* gb1 = (const float*)d_in[19];
  const float* gw2 = (const float*)d_in[20];
  const float* gb2 = (const float*)d_in[21];
  float* ws = (float*)d_ws;
  uint* wsu = (uint*)d_ws;

  hipLaunchKernelGGL(prep_kernel, dim3(304), dim3(256), 0, stream,
                     wih, whh, pw, dw0, dw1, dw2, gw0, gw1, dw3, gw2, ws);
  hipLaunchKernelGGL(gru_kernel, dim3(256), dim3(512), 0, stream,
                     ctp, wsu, gb, gbn, pb, ws);
  hipLaunchKernelGGL(sde_kernel, dim3(512), dim3(256), 0, stream,
                     ctp, dWp, ws, wsu, db0, db1, db2, db3,
                     gb0, gb1, gb2, (float*)d_out);
}

// Round 5
// 219.429 us; speedup vs baseline: 6.0628x; 1.2764x over previous
//
#include <hip/hip_runtime.h>
#include <hip/hip_bf16.h>

typedef unsigned int uint;

#define T_STEPS 32

// ---- workspace dword offsets ----
#define OFF_WB    0        // 30720: GRU B-frags
#define OFF_PJB   30720    // 4096 : proj B-frags (waves 0-3)
#define OFF_D0B   34816    // 6144 : drift_w0 B-frags (KT=3, 89->96 pad)
#define OFF_D1B   40960    // 8192
#define OFF_D2B   49152    // 8192
#define OFF_G0B   57344    // 6144
#define OFF_G1B   63488    // 8192
#define OFF_W3B   71680    // 1024 : drift_w3 head (N pad 15->16)
#define OFF_G2B   72704    // 1024 : diff_w2 head
// end 73728 dwords = 288 KB

typedef _Float16 half8 __attribute__((ext_vector_type(8)));
typedef float    f32x4 __attribute__((ext_vector_type(4)));

union FB { uint4 u4; half8 h; };

__device__ inline uint pack2f(float a, float b) {
  _Float16 ha = (_Float16)a, hb = (_Float16)b;
  unsigned short ua, ub;
  __builtin_memcpy(&ua, &ha, 2);
  __builtin_memcpy(&ub, &hb, 2);
  return (uint)ua | ((uint)ub << 16);
}

__device__ inline float sigm(float x) { return 1.f / (1.f + __expf(-x)); }
__device__ inline float tanh_f(float x) {
  float ax = fabsf(x);
  float e = __expf(2.f * ax);
  float t = 1.f - 2.f / (e + 1.f);
  return copysignf(t, x);
}
__device__ inline float silu_f(float x) { return x / (1.f + __expf(-x)); }

__device__ inline float map89(const float* __restrict__ W, int u, int k) {
  if (k < 25) return W[u * 89 + k];
  if (k < 32) return 0.f;
  return W[u * 89 + k - 7];   // ctx part: 25 + (k-32)
}

// ======================= weight pre-pack =======================
// B-frag format: for (slot, ktile kt): uint i of lane l holds halves
// k = kt*32 + (l>>4)*8 + 2i, 2i+1 of out-unit u = slot*16 + (l&15).
__global__ __launch_bounds__(256) void prep_kernel(
    const float* __restrict__ wih, const float* __restrict__ whh,
    const float* __restrict__ pw,
    const float* __restrict__ dw0, const float* __restrict__ dw1,
    const float* __restrict__ dw2, const float* __restrict__ gw0,
    const float* __restrict__ gw1, const float* __restrict__ dw3,
    const float* __restrict__ gw2, uint* __restrict__ wsu) {
  int id = blockIdx.x * 256 + threadIdx.x;
  if (id < 30720) {
    // GRU: idx = (((w*3+gi)*5+kt)*64 + l)*4 + i ; kt0 = x-part (pad 25->32)
    int i = id & 3, l = (id >> 2) & 63, t3 = id >> 8;
    int kt = t3 % 5, wg = t3 / 5;
    int w = wg / 3, gi = wg % 3;
    int row = gi * 128 + w * 16 + (l & 15);
    int k = ((l >> 4) << 3) + i * 2;
    float a, b;
    if (kt == 0) {
      a = (k     < 25) ? wih[row * 25 + k]     : 0.f;
      b = (k + 1 < 25) ? wih[row * 25 + k + 1] : 0.f;
    } else {
      int kh = (kt - 1) * 32 + k;
      a = whh[row * 128 + kh];
      b = whh[row * 128 + kh + 1];
    }
    wsu[OFF_WB + id] = pack2f(a, b);
  } else if (id < 34816) {               // proj B-frags: (w*4+kt)
    int t = id - 30720;
    int i = t & 3, l = (t >> 2) & 63, wkt = t >> 8;
    int kt = wkt & 3, w = wkt >> 2;
    int u = w * 16 + (l & 15);
    int k = kt * 32 + ((l >> 4) << 3) + i * 2;
    wsu[OFF_PJB + t] = pack2f(pw[u * 128 + k], pw[u * 128 + k + 1]);
  } else if (id < 40960) {               // drift_w0 (89-in, KT=3)
    int t = id - 34816;
    int i = t & 3, l = (t >> 2) & 63, wkt = t >> 8;
    int kt = wkt % 3, w = wkt / 3;
    int u = w * 16 + (l & 15);
    int k = kt * 32 + ((l >> 4) << 3) + i * 2;
    wsu[OFF_D0B + t] = pack2f(map89(dw0, u, k), map89(dw0, u, k + 1));
  } else if (id < 49152) {               // drift_w1
    int t = id - 40960;
    int i = t & 3, l = (t >> 2) & 63, wkt = t >> 8;
    int kt = wkt & 3, w = wkt >> 2;
    int u = w * 16 + (l & 15);
    int k = kt * 32 + ((l >> 4) << 3) + i * 2;
    wsu[OFF_D1B + t] = pack2f(dw1[u * 128 + k], dw1[u * 128 + k + 1]);
  } else if (id < 57344) {               // drift_w2
    int t = id - 49152;
    int i = t & 3, l = (t >> 2) & 63, wkt = t >> 8;
    int kt = wkt & 3, w = wkt >> 2;
    int u = w * 16 + (l & 15);
    int k = kt * 32 + ((l >> 4) << 3) + i * 2;
    wsu[OFF_D2B + t] = pack2f(dw2[u * 128 + k], dw2[u * 128 + k + 1]);
  } else if (id < 63488) {               // diff_w0 (89-in, KT=3)
    int t = id - 57344;
    int i = t & 3, l = (t >> 2) & 63, wkt = t >> 8;
    int kt = wkt % 3, w = wkt / 3;
    int u = w * 16 + (l & 15);
    int k = kt * 32 + ((l >> 4) << 3) + i * 2;
    wsu[OFF_G0B + t] = pack2f(map89(gw0, u, k), map89(gw0, u, k + 1));
  } else if (id < 71680) {               // diff_w1
    int t = id - 63488;
    int i = t & 3, l = (t >> 2) & 63, wkt = t >> 8;
    int kt = wkt & 3, w = wkt >> 2;
    int u = w * 16 + (l & 15);
    int k = kt * 32 + ((l >> 4) << 3) + i * 2;
    wsu[OFF_G1B + t] = pack2f(gw1[u * 128 + k], gw1[u * 128 + k + 1]);
  } else if (id < 72704) {               // drift_w3 head (15 outs, pad 16)
    int t = id - 71680;
    int i = t & 3, l = (t >> 2) & 63, kt = t >> 8;
    int o = l & 15;
    int k = kt * 32 + ((l >> 4) << 3) + i * 2;
    float a = (o < 15) ? dw3[o * 128 + k]     : 0.f;
    float b = (o < 15) ? dw3[o * 128 + k + 1] : 0.f;
    wsu[OFF_W3B + t] = pack2f(a, b);
  } else if (id < 73728) {               // diff_w2 head
    int t = id - 72704;
    int i = t & 3, l = (t >> 2) & 63, kt = t >> 8;
    int o = l & 15;
    int k = kt * 32 + ((l >> 4) << 3) + i * 2;
    float a = (o < 15) ? gw2[o * 128 + k]     : 0.f;
    float b = (o < 15) ? gw2[o * 128 + k + 1] : 0.f;
    wsu[OFF_G2B + t] = pack2f(a, b);
  }
}

// MLP phase: A-frags in LDS (layout [(kt*4+q)*16+e]*8+j), B-frags in VGPRs.
// Wave owns units u = w*16 + (lane&15); lane holds elems lq*4+s of unit u.
template <int KT>
__device__ inline void mlp_phase(const _Float16* __restrict__ aA, const FB* Bf,
                                 float bias, _Float16* __restrict__ outA,
                                 int lm, int lq, int u) {
  f32x4 c = {0.f, 0.f, 0.f, 0.f};
#pragma unroll
  for (int kt = 0; kt < KT; kt++) {
    half8 a = *(const half8*)(aA + ((kt * 4 + lq) * 16 + lm) * 8);
    c = __builtin_amdgcn_mfma_f32_16x16x32_f16(a, Bf[kt].h, c, 0, 0, 0);
  }
  int base = ((u >> 3) * 128) + (u & 7);
#pragma unroll
  for (int s = 0; s < 4; s++)
    outA[base + (lq * 4 + s) * 8] = (_Float16)silu_f(c[s] + bias);
}

__device__ inline float mm5(float A, float Bv, int i, int j) {
  float c = 0.f;
#pragma unroll
  for (int k = 0; k < 5; k++)
    c = fmaf(__shfl(A, i * 5 + k, 32), __shfl(Bv, k * 5 + j, 32), c);
  return c;
}

// ======================= fused GRU + SDE =======================
// grid 256 x 512; block owns 16 batch rows.
__global__ __launch_bounds__(512) void fused_kernel(
    const float* __restrict__ ctp, const float* __restrict__ dWp,
    const uint* __restrict__ wsu,
    const float* __restrict__ gbias, const float* __restrict__ gbn,
    const float* __restrict__ projb,
    const float* __restrict__ db0, const float* __restrict__ db1,
    const float* __restrict__ db2, const float* __restrict__ b3,
    const float* __restrict__ gb0, const float* __restrict__ gb1,
    const float* __restrict__ gb2, float* __restrict__ outp) {
  __shared__ __align__(16) _Float16 bigbuf[16384];           // 32KB: x2 / SDE acts
  __shared__ __align__(16) _Float16 hf[2][4][4][16][8];      // 8KB dbuf h A-frags
  __shared__ float sig_s[16 * 28];
  __shared__ float coeff_s[256];
  __shared__ float coeff2_s[256];
  const int tid = threadIdx.x;
  const int rb = blockIdx.x * 16;
  uint* bigu = (uint*)bigbuf;

  // ---- stage symmetrized features as A-frags (x2 = bigbuf) ----
  for (int idx = tid; idx < T_STEPS * 16 * 16; idx += 512) {
    int k2 = idx & 15, r = (idx >> 4) & 15, t = idx >> 8;
    const float* base = ctp + ((rb + r) * T_STEPS + t) * 25;
    int k0 = 2 * k2;
    float v0 = 0.f, v1 = 0.f;
    if (k0 < 25)     { int i5 = k0 / 5,     j5 = k0 % 5;     v0 = 0.5f * (base[i5*5+j5] + base[j5*5+i5]); }
    if (k0 + 1 < 25) { int i5 = (k0+1) / 5, j5 = (k0+1) % 5; v1 = 0.5f * (base[i5*5+j5] + base[j5*5+i5]); }
    int q = k2 >> 2, jh = k2 & 3;
    bigu[((t * 4 + q) * 16 + r) * 4 + jh] = pack2f(v0, v1);
  }

  const int w = tid >> 6, l = tid & 63;
  const int lm = l & 15, lq = l >> 4;
  const int u = w * 16 + lm;
  const int ku = u >> 5, qu = (u >> 3) & 3, ju = u & 7;
  FB Bf[3][5];
  const uint4* wb = (const uint4*)(wsu + OFF_WB);
#pragma unroll
  for (int gi = 0; gi < 3; gi++)
#pragma unroll
    for (int kt = 0; kt < 5; kt++)
      Bf[gi][kt].u4 = wb[((w * 3 + gi) * 5 + kt) * 64 + l];
  const float br = gbias[u], bz = gbias[128 + u], bg = gbias[256 + u], bn = gbn[u];
  float hprev[4] = {0.f, 0.f, 0.f, 0.f};
  __syncthreads();

  // ---- GRU t-loop (1 barrier/step) ----
  for (int t = 0; t < T_STEPS; t++) {
    half8 ax = *(const half8*)(bigbuf + ((t * 4 + lq) * 16 + lm) * 8);
    f32x4 z4 = {0.f, 0.f, 0.f, 0.f};
    f32x4 cr = __builtin_amdgcn_mfma_f32_16x16x32_f16(ax, Bf[0][0].h, z4, 0, 0, 0);
    f32x4 cz = __builtin_amdgcn_mfma_f32_16x16x32_f16(ax, Bf[1][0].h, z4, 0, 0, 0);
    f32x4 cg = __builtin_amdgcn_mfma_f32_16x16x32_f16(ax, Bf[2][0].h, z4, 0, 0, 0);
    f32x4 ch = {0.f, 0.f, 0.f, 0.f};
    if (t > 0) {
      const int p = t & 1;
#pragma unroll
      for (int kk = 0; kk < 4; kk++) {
        half8 ah = *(const half8*)(&hf[p][kk][lq][lm][0]);
        cr = __builtin_amdgcn_mfma_f32_16x16x32_f16(ah, Bf[0][1 + kk].h, cr, 0, 0, 0);
        cz = __builtin_amdgcn_mfma_f32_16x16x32_f16(ah, Bf[1][1 + kk].h, cz, 0, 0, 0);
        ch = __builtin_amdgcn_mfma_f32_16x16x32_f16(ah, Bf[2][1 + kk].h, ch, 0, 0, 0);
      }
    }
    const int wp = (t + 1) & 1;
#pragma unroll
    for (int s = 0; s < 4; s++) {
      float r = sigm(cr[s] + br);
      float z = sigm(cz[s] + bz);
      float g = tanh_f(cg[s] + bg + r * (ch[s] + bn));
      float hn = (1.f - z) * g + z * hprev[s];
      hprev[s] = hn;
      hf[wp][ku][qu][lq * 4 + s][ju] = (_Float16)hn;
    }
    __syncthreads();
  }

  // ---- SDE B-frag preload (registers) ----
  FB Bd0[3], Bd1[4], Bd2[4], Bg0[3], Bg1[4], Pf[4], Hf4[4];
#pragma unroll
  for (int kt = 0; kt < 3; kt++) {
    Bd0[kt].u4 = ((const uint4*)(wsu + OFF_D0B))[(w * 3 + kt) * 64 + l];
    Bg0[kt].u4 = ((const uint4*)(wsu + OFF_G0B))[(w * 3 + kt) * 64 + l];
  }
#pragma unroll
  for (int kt = 0; kt < 4; kt++) {
    Bd1[kt].u4 = ((const uint4*)(wsu + OFF_D1B))[(w * 4 + kt) * 64 + l];
    Bd2[kt].u4 = ((const uint4*)(wsu + OFF_D2B))[(w * 4 + kt) * 64 + l];
    Bg1[kt].u4 = ((const uint4*)(wsu + OFF_G1B))[(w * 4 + kt) * 64 + l];
  }
  if (w < 4) {
#pragma unroll
    for (int kt = 0; kt < 4; kt++)
      Pf[kt].u4 = ((const uint4*)(wsu + OFF_PJB))[(w * 4 + kt) * 64 + l];
  }
  if (w == 0) {
#pragma unroll
    for (int kt = 0; kt < 4; kt++)
      Hf4[kt].u4 = ((const uint4*)(wsu + OFF_W3B))[kt * 64 + l];
  } else if (w == 1) {
#pragma unroll
    for (int kt = 0; kt < 4; kt++)
      Hf4[kt].u4 = ((const uint4*)(wsu + OFF_G2B))[kt * 64 + l];
  }
  const float bd0v = db0[u], bd1v = db1[u], bd2v = db2[u];
  const float bg0v = gb0[u], bg1v = gb1[u];
  const int oc = (lm < 15) ? lm : 0;
  const float hb = (w == 0) ? b3[oc] : ((w == 1) ? gb2[oc] : 0.f);

  _Float16* inpA = bigbuf;          // 3 ktiles (k: 0-24 sigma | pad | 32-95 ctx)
  _Float16* actA = bigbuf + 1536;
  _Float16* actB = bigbuf + 3584;
  _Float16* actC = bigbuf + 5632;

  // proj via MFMA (waves 0-3): ctx -> inpA ctx part
  if (w < 4) {
    f32x4 c = {0.f, 0.f, 0.f, 0.f};
#pragma unroll
    for (int kt = 0; kt < 4; kt++) {
      half8 a = *(const half8*)(&hf[0][kt][lq][lm][0]);
      c = __builtin_amdgcn_mfma_f32_16x16x32_f16(a, Pf[kt].h, c, 0, 0, 0);
    }
    const float pbv = projb[u];
    int kk = 32 + u, base = (kk >> 3) * 128 + (kk & 7);
#pragma unroll
    for (int s = 0; s < 4; s++)
      inpA[base + (lq * 4 + s) * 8] = (_Float16)(c[s] + pbv);
  }
  // sigma init + pad
  for (int idx = tid; idx < 400; idx += 512) {
    int e = idx / 25, k = idx % 25;
    int i5 = k / 5, j5 = k % 5;
    const float* base = ctp + ((rb + e) * T_STEPS + 31) * 25;
    float v = 0.5f * (base[i5 * 5 + j5] + base[j5 * 5 + i5]);
    sig_s[e * 28 + k] = v;
    inpA[(k >> 3) * 128 + e * 8 + (k & 7)] = (_Float16)v;
  }
  if (tid < 112) {
    int e = tid / 7, p = 25 + tid % 7;
    inpA[(p >> 3) * 128 + e * 8 + (p & 7)] = (_Float16)0.f;
  }
  __syncthreads();

  // ---- SDE step loop ----
  for (int st = 0; st < 5; st++) {
    float dwv[4];
    if (w == 1) {
#pragma unroll
      for (int s = 0; s < 4; s++)
        dwv[s] = dWp[((rb + lq * 4 + s) * 5 + st) * 15 + oc];
    }
    mlp_phase<3>(inpA, Bg0, bg0v, actA, lm, lq, u); __syncthreads();   // g0
    mlp_phase<4>(actA, Bg1, bg1v, actB, lm, lq, u); __syncthreads();   // g1
    mlp_phase<3>(inpA, Bd0, bd0v, actA, lm, lq, u); __syncthreads();   // d0
    mlp_phase<4>(actA, Bd1, bd1v, actC, lm, lq, u); __syncthreads();   // d1
    mlp_phase<4>(actC, Bd2, bd2v, actA, lm, lq, u); __syncthreads();   // d2

    // heads: wave0 drift(actA), wave1 diff(actB)
    if (w == 0) {
      f32x4 c = {0.f, 0.f, 0.f, 0.f};
#pragma unroll
      for (int kt = 0; kt < 4; kt++) {
        half8 a = *(const half8*)(actA + ((kt * 4 + lq) * 16 + lm) * 8);
        c = __builtin_amdgcn_mfma_f32_16x16x32_f16(a, Hf4[kt].h, c, 0, 0, 0);
      }
      if (lm < 15) {
#pragma unroll
        for (int s = 0; s < 4; s++)
          coeff_s[(lq * 4 + s) * 16 + lm] = 0.2f * (c[s] + hb);
      }
    } else if (w == 1) {
      f32x4 c = {0.f, 0.f, 0.f, 0.f};
#pragma unroll
      for (int kt = 0; kt < 4; kt++) {
        half8 a = *(const half8*)(actB + ((kt * 4 + lq) * 16 + lm) * 8);
        c = __builtin_amdgcn_mfma_f32_16x16x32_f16(a, Hf4[kt].h, c, 0, 0, 0);
      }
      if (lm < 15) {
#pragma unroll
        for (int s = 0; s < 4; s++) {
          float acc = c[s] + hb;
          float sp = (acc > 20.f) ? acc : __logf(1.f + __expf(acc));
          coeff2_s[(lq * 4 + s) * 16 + lm] = sp * dwv[s];
        }
      }
    }
    __syncthreads();

    // ---- geometry: 32-lane group per element (16 groups) ----
    {
      int e = tid >> 5;
      int lane = tid & 31;
      int li = (lane < 25) ? lane : 0;
      int ii = li / 5, jj2 = li % 5;
      float del = (ii == jj2) ? 1.f : 0.f;
      float S = sig_s[e * 28 + li];
      float tr = 0.f;
#pragma unroll
      for (int d = 0; d < 5; d++) tr += __shfl(S, d * 6, 32);
      float Y = S * (1.f / tr);
      float Z = del;
      for (int it = 0; it < 15; it++) {
        float P  = mm5(Z, Y, ii, jj2);
        float Tm = 1.5f * del - 0.5f * P;
        float Yn = mm5(Y, Tm, ii, jj2);
        float Zn = mm5(Tm, Z, ii, jj2);
        Y = Yn; Z = Zn;
      }
      float L = Y * sqrtf(tr);
      float av;
      if (ii == jj2) av = coeff_s[e * 16 + ii] + coeff2_s[e * 16 + ii];
      else {
        int p = ii < jj2 ? ii : jj2, qq = ii < jj2 ? jj2 : ii;
        int i5 = 5 + (p * (9 - p)) / 2 + (qq - p - 1);
        av = (coeff_s[e * 16 + i5] + coeff2_s[e * 16 + i5]) * 0.70710678f;
      }
      float M = del;
#pragma unroll
      for (int n = 12; n >= 1; n--) {
        float P = mm5(av, M, ii, jj2);
        M = del + P * (1.f / (float)n);
      }
      float P2 = mm5(L, M, ii, jj2);
      float S2 = mm5(P2, L, ii, jj2);
      S2 = 0.5f * (S2 + __shfl(S2, jj2 * 5 + ii, 32));
      if (lane < 25) {
        sig_s[e * 28 + li] = S2;
        inpA[(li >> 3) * 128 + e * 8 + (li & 7)] = (_Float16)S2;
      }
    }
    __syncthreads();
  }

  for (int idx = tid; idx < 400; idx += 512) {
    int e = idx / 25, k = idx % 25;
    outp[(rb + e) * 25 + k] = sig_s[e * 28 + k];
  }
}

extern "C" void kernel_launch(void* const* d_in, const int* in_sizes, int n_in,
                              void* d_out, int out_size, void* d_ws, size_t ws_size,
                              hipStream_t stream) {
  const float* ctp = (const float*)d_in[0];
  const float* dWp = (const float*)d_in[1];
  const float* wih = (const float*)d_in[2];
  const float* whh = (const float*)d_in[3];
  const float* gb  = (const float*)d_in[4];
  const float* gbn = (const float*)d_in[5];
  const float* pw  = (const float*)d_in[6];
  const float* pb  = (const float*)d_in[7];
  const float* dw0 = (const float*)d_in[8];
  const float* db0 = (const float*)d_in[9];
  const float* dw1 = (const float*)d_in[10];
  const float* db1 = (const float*)d_in[11];
  const float* dw2 = (const float*)d_in[12];
  const float* db2 = (const float*)d_in[13];
  const float* dw3 = (const float*)d_in[14];
  const float* db3 = (const float*)d_in[15];
  const float* gw0 = (const float*)d_in[16];
  const float* gb0 = (const float*)d_in[17];
  const float* gw1 = (const float*)d_in[18];
  const float* gb1 = (const float*)d_in[19];
  const float* gw2 = (const float*)d_in[20];
  const float* gb2 = (const float*)d_in[21];
  uint* wsu = (uint*)d_ws;

  hipLaunchKernelGGL(prep_kernel, dim3(288), dim3(256), 0, stream,
                     wih, whh, pw, dw0, dw1, dw2, gw0, gw1, dw3, gw2, wsu);
  hipLaunchKernelGGL(fused_kernel, dim3(256), dim3(512), 0, stream,
                     ctp, dWp, wsu, gb, gbn, pb,
                     db0, db1, db2, db3, gb0, gb1, gb2, (float*)d_out);
}